// Round 1
// baseline (59.935 us; speedup 1.0000x reference)
//
#include <hip/hip_runtime.h>

#define NROWS (64 * 2048)            // 131072 rows (B*T)
#define VDIM  128                    // pitch vocabulary
#define NELEM (16777216.0f)          // NROWS * VDIM = 2^24 (exact in fp32)

__constant__ float c_quality[12] = {1.0f, 0.5f, 0.3f, 0.2f, 0.1f, 0.1f,
                                    0.7f, 0.0f, 0.2f, 0.3f, 0.4f, 0.5f};

__global__ __launch_bounds__(256) void mtl_kernel(const float* __restrict__ outputs,
                                                  const float* __restrict__ targets,
                                                  const float* __restrict__ melodies,
                                                  float* __restrict__ out) {
    const int tid  = threadIdx.x;
    const int lane = tid & 63;
    const int wid  = tid >> 6;                 // wave in block: 0..3
    const int gw   = blockIdx.x * 4 + wid;     // global wave id
    const int GW   = gridDim.x * 4;            // total waves
    const int half = lane >> 5;                // 0 or 1: which row of the pair
    const int l32  = lane & 31;                // position within 32-lane group

    float msum = 0.0f;   // sum of squared diffs (this lane)
    float hsum = 0.0f;   // sum of quality values (only l32==0 lanes contribute)

    for (int rp = gw; rp < NROWS / 2; rp += GW) {
        const int row = rp * 2 + half;
        const float4* op = reinterpret_cast<const float4*>(outputs  + (size_t)row * VDIM);
        const float4* tp = reinterpret_cast<const float4*>(targets  + (size_t)row * VDIM);
        const float4* mp = reinterpret_cast<const float4*>(melodies + (size_t)row * VDIM);
        float4 o = op[l32];
        float4 t = tp[l32];
        float4 m = mp[l32];

        // --- MSE partial ---
        float dx = o.x - t.x, dy = o.y - t.y, dz = o.z - t.z, dw = o.w - t.w;
        msum = fmaf(dx, dx, msum);
        msum = fmaf(dy, dy, msum);
        msum = fmaf(dz, dz, msum);
        msum = fmaf(dw, dw, msum);

        // --- local argmax over this lane's 4 elements (first index wins ties) ---
        float ov = o.x; int oi = 0;
        if (o.y > ov) { ov = o.y; oi = 1; }
        if (o.z > ov) { ov = o.z; oi = 2; }
        if (o.w > ov) { ov = o.w; oi = 3; }
        oi += l32 * 4;
        float mv = m.x; int mi = 0;
        if (m.y > mv) { mv = m.y; mi = 1; }
        if (m.z > mv) { mv = m.z; mi = 2; }
        if (m.w > mv) { mv = m.w; mi = 3; }
        mi += l32 * 4;

        // --- argmax butterfly within each 32-lane group (xor 1..16 never crosses bit 5) ---
        #pragma unroll
        for (int off = 16; off >= 1; off >>= 1) {
            float ov2 = __shfl_xor(ov, off);
            int   oi2 = __shfl_xor(oi, off);
            if (ov2 > ov || (ov2 == ov && oi2 < oi)) { ov = ov2; oi = oi2; }
            float mv2 = __shfl_xor(mv, off);
            int   mi2 = __shfl_xor(mi, off);
            if (mv2 > mv || (mv2 == mv && mi2 < mi)) { mv = mv2; mi = mi2; }
        }

        if (l32 == 0) {
            int d = mi - oi;
            if (d < 0) d = -d;
            hsum += c_quality[d % 12];
        }
    }

    // --- full-wave reduction of both partials ---
    #pragma unroll
    for (int off = 32; off >= 1; off >>= 1) {
        msum += __shfl_xor(msum, off);
        hsum += __shfl_xor(hsum, off);
    }

    __shared__ float s_m[4];
    __shared__ float s_h[4];
    if (lane == 0) { s_m[wid] = msum; s_h[wid] = hsum; }
    __syncthreads();

    if (tid == 0) {
        float mt = s_m[0] + s_m[1] + s_m[2] + s_m[3];
        float ht = s_h[0] + s_h[1] + s_h[2] + s_h[3];
        // pre-scale so a single atomicAdd per block produces the final scalar
        float contrib = mt * (1.0f / NELEM) + ht * (1.0f / (float)NROWS);
        atomicAdd(out, contrib);
    }
}

extern "C" void kernel_launch(void* const* d_in, const int* in_sizes, int n_in,
                              void* d_out, int out_size, void* d_ws, size_t ws_size,
                              hipStream_t stream) {
    const float* outputs  = (const float*)d_in[0];
    const float* targets  = (const float*)d_in[1];
    const float* melodies = (const float*)d_in[2];
    float* out = (float*)d_out;

    // d_out is poisoned once and never re-zeroed between replays; zero it on-stream.
    hipMemsetAsync(out, 0, sizeof(float), stream);

    const int blocks = 2048;   // 8192 waves = 32 waves/CU; 8 row-pair iters each
    mtl_kernel<<<blocks, 256, 0, stream>>>(outputs, targets, melodies, out);
}

// Round 2
// 51.309 us; speedup vs baseline: 1.1681x; 1.1681x over previous
//
#include <hip/hip_runtime.h>

#define BLOCKS 2048
#define TPB    256
#define WAVES  (BLOCKS * (TPB / 64))     // 8192 waves
#define NROWS  (64 * 2048)               // 131072 rows (B*T)
#define PAIRS  (NROWS / 2)               // 65536 row-pairs
#define ITERS  (PAIRS / WAVES)           // 8 iterations per wave (exact)
#define VDIM   128
#define NELEM  16777216.0f               // NROWS*VDIM = 2^24, exact in fp32

// quality[i] = 0.1 * nib[i]; nib = {10,5,3,2,1,1,7,0,2,3,4,5} packed low->high
#define QTAB 0x54320711235AULL

// monotonic float->u32 key: ordering of floats == unsigned ordering of keys
__device__ __forceinline__ unsigned int fkey(float f) {
    unsigned int u = __float_as_uint(f);
    unsigned int m = ((unsigned int)((int)u >> 31)) | 0x80000000u;
    return u ^ m;   // pos: u|0x80000000 ; neg: ~u
}

// max over each 16-lane DPP row via cyclic rotations (all lanes get row max)
__device__ __forceinline__ unsigned int rowmax16(unsigned int k) {
    unsigned int t;
    t = (unsigned int)__builtin_amdgcn_update_dpp(0, (int)k, 0x121, 0xF, 0xF, true); // row_ror:1
    k = k > t ? k : t;
    t = (unsigned int)__builtin_amdgcn_update_dpp(0, (int)k, 0x122, 0xF, 0xF, true); // row_ror:2
    k = k > t ? k : t;
    t = (unsigned int)__builtin_amdgcn_update_dpp(0, (int)k, 0x124, 0xF, 0xF, true); // row_ror:4
    k = k > t ? k : t;
    t = (unsigned int)__builtin_amdgcn_update_dpp(0, (int)k, 0x128, 0xF, 0xF, true); // row_ror:8
    k = k > t ? k : t;
    return k;
}

// local argmax over this lane's float4 (first index wins ties) -> packed key
__device__ __forceinline__ unsigned int lane_key(float4 v, int l32) {
    float bv = v.x; int bi = 0;
    if (v.y > bv) { bv = v.y; bi = 1; }
    if (v.z > bv) { bv = v.z; bi = 2; }
    if (v.w > bv) { bv = v.w; bi = 3; }
    int idx = l32 * 4 + bi;                       // 0..127
    return (fkey(bv) & 0xFFFFFF80u) | (unsigned int)(127 - idx);
}

__global__ __launch_bounds__(TPB) void mtl_kernel(const float* __restrict__ outputs,
                                                  const float* __restrict__ targets,
                                                  const float* __restrict__ melodies,
                                                  float* __restrict__ out) {
    const int tid  = threadIdx.x;
    const int lane = tid & 63;
    const int wid  = tid >> 6;
    const int gw   = blockIdx.x * (TPB / 64) + wid;   // global wave id
    const int half = lane >> 5;                        // which row of the pair
    const int l32  = lane & 31;

    // per-wave base: float4 index for (row = 2*gw + half), element chunk l32
    const size_t base = (size_t)(2 * gw + half) * (VDIM / 4) + l32;
    const float4* __restrict__ ob = reinterpret_cast<const float4*>(outputs)  + base;
    const float4* __restrict__ tb = reinterpret_cast<const float4*>(targets)  + base;
    const float4* __restrict__ mb = reinterpret_cast<const float4*>(melodies) + base;
    const size_t step = (size_t)WAVES * 2 * (VDIM / 4);  // float4s per iteration

    float msum = 0.0f;
    float hsum = 0.0f;   // accumulated by ALL lanes (32x redundant), scaled later

    float4 o = ob[0], t = tb[0], m = mb[0];

    #pragma unroll
    for (int it = 0; it < ITERS; ++it) {
        // prefetch next row-pair before touching current data
        float4 on = o, tn = t, mn = m;
        if (it + 1 < ITERS) {
            size_t noff = (size_t)(it + 1) * step;
            on = ob[noff]; tn = tb[noff]; mn = mb[noff];
        }

        // --- MSE partial ---
        float dx = o.x - t.x, dy = o.y - t.y, dz = o.z - t.z, dw = o.w - t.w;
        msum = fmaf(dx, dx, msum);
        msum = fmaf(dy, dy, msum);
        msum = fmaf(dz, dz, msum);
        msum = fmaf(dw, dw, msum);

        // --- argmax keys: DPP row-reduce + one cross-row shuffle ---
        unsigned int ok = lane_key(o, l32);
        unsigned int mk = lane_key(m, l32);
        ok = rowmax16(ok);
        mk = rowmax16(mk);
        unsigned int ok2 = (unsigned int)__shfl_xor((int)ok, 16);
        unsigned int mk2 = (unsigned int)__shfl_xor((int)mk, 16);
        ok = ok > ok2 ? ok : ok2;    // all 32 lanes of the group now hold row argmax key
        mk = mk > mk2 ? mk : mk2;

        int oi = 127 - (int)(ok & 127u);
        int mi = 127 - (int)(mk & 127u);
        int d = mi - oi;
        if (d < 0) d = -d;
        int interval = d % 12;
        float q = (float)((unsigned int)(QTAB >> (interval << 2)) & 15u) * 0.1f;
        hsum += q;

        o = on; t = tn; m = mn;
    }

    // --- full-wave reduction ---
    #pragma unroll
    for (int off = 32; off >= 1; off >>= 1) {
        msum += __shfl_xor(msum, off);
        hsum += __shfl_xor(hsum, off);
    }

    __shared__ float s_m[TPB / 64];
    __shared__ float s_h[TPB / 64];
    if (lane == 0) { s_m[wid] = msum; s_h[wid] = hsum; }
    __syncthreads();

    if (tid == 0) {
        float mt = s_m[0] + s_m[1] + s_m[2] + s_m[3];
        float ht = s_h[0] + s_h[1] + s_h[2] + s_h[3];
        // hsum counted each row 32x; NROWS*32 = 2^22
        float contrib = mt * (1.0f / NELEM) + ht * (1.0f / 4194304.0f);
        atomicAdd(out, contrib);
    }
}

extern "C" void kernel_launch(void* const* d_in, const int* in_sizes, int n_in,
                              void* d_out, int out_size, void* d_ws, size_t ws_size,
                              hipStream_t stream) {
    const float* outputs  = (const float*)d_in[0];
    const float* targets  = (const float*)d_in[1];
    const float* melodies = (const float*)d_in[2];
    float* out = (float*)d_out;

    hipMemsetAsync(out, 0, sizeof(float), stream);
    mtl_kernel<<<BLOCKS, TPB, 0, stream>>>(outputs, targets, melodies, out);
}

// Round 3
// 48.718 us; speedup vs baseline: 1.2302x; 1.0532x over previous
//
#include <hip/hip_runtime.h>

#define BLOCKS 2048
#define TPB    256
#define WAVES  (BLOCKS * (TPB / 64))     // 8192 waves
#define NROWS  (64 * 2048)               // 131072 rows (B*T)
#define PAIRS  (NROWS / 2)               // 65536 row-pairs
#define ITERS  (PAIRS / WAVES)           // 8 iterations per wave (exact)
#define VDIM   128
#define NELEM  16777216.0f               // NROWS*VDIM = 2^24, exact in fp32

// quality[i] = 0.1 * nib[i]; nib = {10,5,3,2,1,1,7,0,2,3,4,5} packed low->high
#define QTAB 0x54320711235AULL

// monotonic float->u32 key: ordering of floats == unsigned ordering of keys
__device__ __forceinline__ unsigned int fkey(float f) {
    unsigned int u = __float_as_uint(f);
    unsigned int m = ((unsigned int)((int)u >> 31)) | 0x80000000u;
    return u ^ m;   // pos: u|0x80000000 ; neg: ~u
}

// max over each 16-lane DPP row via cyclic rotations (all lanes get row max)
__device__ __forceinline__ unsigned int rowmax16(unsigned int k) {
    unsigned int t;
    t = (unsigned int)__builtin_amdgcn_update_dpp(0, (int)k, 0x121, 0xF, 0xF, true); // row_ror:1
    k = k > t ? k : t;
    t = (unsigned int)__builtin_amdgcn_update_dpp(0, (int)k, 0x122, 0xF, 0xF, true); // row_ror:2
    k = k > t ? k : t;
    t = (unsigned int)__builtin_amdgcn_update_dpp(0, (int)k, 0x124, 0xF, 0xF, true); // row_ror:4
    k = k > t ? k : t;
    t = (unsigned int)__builtin_amdgcn_update_dpp(0, (int)k, 0x128, 0xF, 0xF, true); // row_ror:8
    k = k > t ? k : t;
    return k;
}

// local argmax over this lane's float4 (first index wins ties) -> packed key
__device__ __forceinline__ unsigned int lane_key(float4 v, int l32) {
    float bv = v.x; int bi = 0;
    if (v.y > bv) { bv = v.y; bi = 1; }
    if (v.z > bv) { bv = v.z; bi = 2; }
    if (v.w > bv) { bv = v.w; bi = 3; }
    int idx = l32 * 4 + bi;                       // 0..127
    return (fkey(bv) & 0xFFFFFF80u) | (unsigned int)(127 - idx);
}

__global__ __launch_bounds__(TPB) void mtl_kernel(const float* __restrict__ outputs,
                                                  const float* __restrict__ targets,
                                                  const float* __restrict__ melodies,
                                                  float* __restrict__ out) {
    const int tid  = threadIdx.x;
    const int lane = tid & 63;
    const int wid  = tid >> 6;
    const int gw   = blockIdx.x * (TPB / 64) + wid;   // global wave id
    const int half = lane >> 5;                        // which row of the pair
    const int l32  = lane & 31;

    // per-wave base: float4 index for (row = 2*gw + half), element chunk l32
    const size_t base = (size_t)(2 * gw + half) * (VDIM / 4) + l32;
    const float4* __restrict__ ob = reinterpret_cast<const float4*>(outputs)  + base;
    const float4* __restrict__ tb = reinterpret_cast<const float4*>(targets)  + base;
    const float4* __restrict__ mb = reinterpret_cast<const float4*>(melodies) + base;
    const size_t step = (size_t)WAVES * 2 * (VDIM / 4);  // float4 stride per iteration

    // ---- issue ALL loads first: 24 outstanding global_load_dwordx4 per lane ----
    float4 O[ITERS], T[ITERS], M[ITERS];
    #pragma unroll
    for (int i = 0; i < ITERS; ++i) {
        size_t off = (size_t)i * step;
        O[i] = ob[off];
        T[i] = tb[off];
        M[i] = mb[off];
    }

    float msum = 0.0f;
    float hsum = 0.0f;   // accumulated by ALL lanes (32x redundant), scaled later

    #pragma unroll
    for (int i = 0; i < ITERS; ++i) {
        float4 o = O[i], t = T[i], m = M[i];

        // --- MSE partial ---
        float dx = o.x - t.x, dy = o.y - t.y, dz = o.z - t.z, dw = o.w - t.w;
        msum = fmaf(dx, dx, msum);
        msum = fmaf(dy, dy, msum);
        msum = fmaf(dz, dz, msum);
        msum = fmaf(dw, dw, msum);

        // --- argmax keys: DPP row-reduce + one cross-row shuffle ---
        unsigned int ok = lane_key(o, l32);
        unsigned int mk = lane_key(m, l32);
        ok = rowmax16(ok);
        mk = rowmax16(mk);
        unsigned int ok2 = (unsigned int)__shfl_xor((int)ok, 16);
        unsigned int mk2 = (unsigned int)__shfl_xor((int)mk, 16);
        ok = ok > ok2 ? ok : ok2;    // all 32 lanes of the group now hold row argmax key
        mk = mk > mk2 ? mk : mk2;

        int oi = 127 - (int)(ok & 127u);
        int mi = 127 - (int)(mk & 127u);
        int d = mi - oi;
        if (d < 0) d = -d;
        int interval = d % 12;
        float q = (float)((unsigned int)(QTAB >> (interval << 2)) & 15u) * 0.1f;
        hsum += q;
    }

    // --- full-wave reduction ---
    #pragma unroll
    for (int off = 32; off >= 1; off >>= 1) {
        msum += __shfl_xor(msum, off);
        hsum += __shfl_xor(hsum, off);
    }

    __shared__ float s_m[TPB / 64];
    __shared__ float s_h[TPB / 64];
    if (lane == 0) { s_m[wid] = msum; s_h[wid] = hsum; }
    __syncthreads();

    if (tid == 0) {
        float mt = s_m[0] + s_m[1] + s_m[2] + s_m[3];
        float ht = s_h[0] + s_h[1] + s_h[2] + s_h[3];
        // hsum counted each row 32x; NROWS*32 = 2^22
        float contrib = mt * (1.0f / NELEM) + ht * (1.0f / 4194304.0f);
        atomicAdd(out, contrib);
    }
}

extern "C" void kernel_launch(void* const* d_in, const int* in_sizes, int n_in,
                              void* d_out, int out_size, void* d_ws, size_t ws_size,
                              hipStream_t stream) {
    const float* outputs  = (const float*)d_in[0];
    const float* targets  = (const float*)d_in[1];
    const float* melodies = (const float*)d_in[2];
    float* out = (float*)d_out;

    hipMemsetAsync(out, 0, sizeof(float), stream);
    mtl_kernel<<<BLOCKS, TPB, 0, stream>>>(outputs, targets, melodies, out);
}

// Round 4
// 48.427 us; speedup vs baseline: 1.2376x; 1.0060x over previous
//
#include <hip/hip_runtime.h>

#define BLOCKS 2048
#define TPB    256
#define WAVES  (BLOCKS * (TPB / 64))     // 8192 waves
#define NROWS  (64 * 2048)               // 131072 rows (B*T)
#define PAIRS  (NROWS / 2)               // 65536 row-pairs
#define ITERS  (PAIRS / WAVES)           // 8 iterations per wave (exact)
#define VDIM   128
#define NELEM  16777216.0f               // NROWS*VDIM = 2^24, exact in fp32

// quality[i] = 0.1 * nib[i]; nib = {10,5,3,2,1,1,7,0,2,3,4,5} packed low->high
#define QTAB 0x54320711235AULL

// monotonic float->u32 key: ordering of floats == unsigned ordering of keys
__device__ __forceinline__ unsigned int fkey(float f) {
    unsigned int u = __float_as_uint(f);
    unsigned int m = ((unsigned int)((int)u >> 31)) | 0x80000000u;
    return u ^ m;   // pos: u|0x80000000 ; neg: ~u
}

// max over each 16-lane DPP row via cyclic rotations (all lanes get row max)
__device__ __forceinline__ unsigned int rowmax16(unsigned int k) {
    unsigned int t;
    t = (unsigned int)__builtin_amdgcn_update_dpp(0, (int)k, 0x121, 0xF, 0xF, true); // row_ror:1
    k = k > t ? k : t;
    t = (unsigned int)__builtin_amdgcn_update_dpp(0, (int)k, 0x122, 0xF, 0xF, true); // row_ror:2
    k = k > t ? k : t;
    t = (unsigned int)__builtin_amdgcn_update_dpp(0, (int)k, 0x124, 0xF, 0xF, true); // row_ror:4
    k = k > t ? k : t;
    t = (unsigned int)__builtin_amdgcn_update_dpp(0, (int)k, 0x128, 0xF, 0xF, true); // row_ror:8
    k = k > t ? k : t;
    return k;
}

// local argmax over this lane's float4 (first index wins ties) -> packed key
__device__ __forceinline__ unsigned int lane_key(float4 v, int l32) {
    float bv = v.x; int bi = 0;
    if (v.y > bv) { bv = v.y; bi = 1; }
    if (v.z > bv) { bv = v.z; bi = 2; }
    if (v.w > bv) { bv = v.w; bi = 3; }
    int idx = l32 * 4 + bi;                       // 0..127
    return (fkey(bv) & 0xFFFFFF80u) | (unsigned int)(127 - idx);
}

__global__ __launch_bounds__(TPB) void mtl_kernel(const float* __restrict__ outputs,
                                                  const float* __restrict__ targets,
                                                  const float* __restrict__ melodies,
                                                  float* __restrict__ out) {
    const int tid  = threadIdx.x;
    const int lane = tid & 63;
    const int wid  = tid >> 6;
    const int gw   = blockIdx.x * (TPB / 64) + wid;   // global wave id
    const int half = lane >> 5;                        // which row of the pair
    const int l32  = lane & 31;

    // per-wave base: float4 index for (row = 2*gw + half), element chunk l32
    const size_t base = (size_t)(2 * gw + half) * (VDIM / 4) + l32;
    const float4* __restrict__ ob = reinterpret_cast<const float4*>(outputs)  + base;
    const float4* __restrict__ tb = reinterpret_cast<const float4*>(targets)  + base;
    const float4* __restrict__ mb = reinterpret_cast<const float4*>(melodies) + base;
    const size_t step = (size_t)WAVES * 2 * (VDIM / 4);  // float4 stride per iteration

    // ---- issue ALL loads first: 24 outstanding global_load_dwordx4 per lane ----
    float4 O[ITERS], T[ITERS], M[ITERS];
    #pragma unroll
    for (int i = 0; i < ITERS; ++i) {
        size_t off = (size_t)i * step;
        O[i] = ob[off];
        T[i] = tb[off];
        M[i] = mb[off];
    }

    // HARD scheduling fence: nothing moves across this point. All 24
    // global_load_dwordx4 must be issued before any compute below; the
    // compiler then uses counted vmcnt waits (21,18,...) inside the
    // compute block instead of sinking loads to their uses.
    __builtin_amdgcn_sched_barrier(0);

    float msum = 0.0f;
    float hsum = 0.0f;   // accumulated by ALL lanes (32x redundant), scaled later

    #pragma unroll
    for (int i = 0; i < ITERS; ++i) {
        float4 o = O[i], t = T[i], m = M[i];

        // --- MSE partial ---
        float dx = o.x - t.x, dy = o.y - t.y, dz = o.z - t.z, dw = o.w - t.w;
        msum = fmaf(dx, dx, msum);
        msum = fmaf(dy, dy, msum);
        msum = fmaf(dz, dz, msum);
        msum = fmaf(dw, dw, msum);

        // --- argmax keys: DPP row-reduce + one cross-row shuffle ---
        unsigned int ok = lane_key(o, l32);
        unsigned int mk = lane_key(m, l32);
        ok = rowmax16(ok);
        mk = rowmax16(mk);
        unsigned int ok2 = (unsigned int)__shfl_xor((int)ok, 16);
        unsigned int mk2 = (unsigned int)__shfl_xor((int)mk, 16);
        ok = ok > ok2 ? ok : ok2;    // all 32 lanes of the group now hold row argmax key
        mk = mk > mk2 ? mk : mk2;

        int oi = 127 - (int)(ok & 127u);
        int mi = 127 - (int)(mk & 127u);
        int d = mi - oi;
        if (d < 0) d = -d;
        int interval = d % 12;
        float q = (float)((unsigned int)(QTAB >> (interval << 2)) & 15u) * 0.1f;
        hsum += q;
    }

    // --- full-wave reduction ---
    #pragma unroll
    for (int off = 32; off >= 1; off >>= 1) {
        msum += __shfl_xor(msum, off);
        hsum += __shfl_xor(hsum, off);
    }

    __shared__ float s_m[TPB / 64];
    __shared__ float s_h[TPB / 64];
    if (lane == 0) { s_m[wid] = msum; s_h[wid] = hsum; }
    __syncthreads();

    if (tid == 0) {
        float mt = s_m[0] + s_m[1] + s_m[2] + s_m[3];
        float ht = s_h[0] + s_h[1] + s_h[2] + s_h[3];
        // hsum counted each row 32x; NROWS*32 = 2^22
        float contrib = mt * (1.0f / NELEM) + ht * (1.0f / 4194304.0f);
        atomicAdd(out, contrib);
    }
}

extern "C" void kernel_launch(void* const* d_in, const int* in_sizes, int n_in,
                              void* d_out, int out_size, void* d_ws, size_t ws_size,
                              hipStream_t stream) {
    const float* outputs  = (const float*)d_in[0];
    const float* targets  = (const float*)d_in[1];
    const float* melodies = (const float*)d_in[2];
    float* out = (float*)d_out;

    hipMemsetAsync(out, 0, sizeof(float), stream);
    mtl_kernel<<<BLOCKS, TPB, 0, stream>>>(outputs, targets, melodies, out);
}